// Round 7
// baseline (791.575 us; speedup 1.0000x reference)
//
#include <hip/hip_runtime.h>
#include <hip/hip_bf16.h>
#include <stdint.h>

#define M_DIM 16384   // B*S = 4*4096
#define N_DIM 4096    // OUT
#define K_DIM 4096    // IN
#define NT32  (K_DIM / 32)   // 128 K-tiles of BK=32

typedef float f32x4  __attribute__((ext_vector_type(4)));
typedef short bf16x8 __attribute__((ext_vector_type(8)));
typedef unsigned short u16;

__device__ __forceinline__ unsigned short f32_to_bf16(float f) {
    union { float f; uint32_t u; } v; v.f = f;
    uint32_t u = v.u;
    uint32_t r = (u + 0x7FFFu + ((u >> 16) & 1u)) >> 16;   // RNE
    return (unsigned short)r;
}

__device__ __forceinline__ void gload16(const void* g, void* l) {
    __builtin_amdgcn_global_load_lds(
        (const __attribute__((address_space(1))) void*)g,
        (__attribute__((address_space(3))) void*)l,
        16, 0, 0);
}

// ---------------------------------------------------------------------------
// Fused prep: blocks [0,16384): Weff build; blocks [16384,49152): x cvt.
// Weff[o][i] = bf16( W0[o][i] + 0.25 * w1[o>>6][i>>6] * w2[o&63][i&63] )
// ---------------------------------------------------------------------------
__global__ void prep(const float* __restrict__ W0,
                     const float* __restrict__ w1,
                     const float* __restrict__ w2a,
                     const float* __restrict__ w2b,
                     const float* __restrict__ x,
                     u16* __restrict__ Weff,
                     u16* __restrict__ xb) {
    const int bid = blockIdx.x;
    if (bid < 16384) {
        long idx = (long)bid * 256 + threadIdx.x;   // over N*K/4
        long e0 = idx * 4;
        int o  = (int)(e0 >> 12);
        int i0 = (int)(e0 & 4095);
        int r  = o & 63;
        float a0 = w2a[r * 4 + 0], a1 = w2a[r * 4 + 1];
        float a2 = w2a[r * 4 + 2], a3 = w2a[r * 4 + 3];
        float w1v = w1[(o >> 6) * 64 + (i0 >> 6)] * 0.25f;
        float4 w0 = *(const float4*)(W0 + e0);
        const float* w0p = (const float*)&w0;
        unsigned short outp[4];
#pragma unroll
        for (int j = 0; j < 4; ++j) {
            int c = (i0 + j) & 63;
            float w2 = a0 * w2b[0 * 64 + c] + a1 * w2b[1 * 64 + c]
                     + a2 * w2b[2 * 64 + c] + a3 * w2b[3 * 64 + c];
            outp[j] = f32_to_bf16(w0p[j] + w1v * w2);
        }
        *(ushort4*)(Weff + e0) = make_ushort4(outp[0], outp[1], outp[2], outp[3]);
    } else {
        long idx = (long)(bid - 16384) * 256 + threadIdx.x;   // over M*K/8
        long e0 = idx * 8;
        float4 v0 = *(const float4*)(x + e0);
        float4 v1 = *(const float4*)(x + e0 + 4);
        union { unsigned short s[8]; int4 v; } o;
        const float* p0 = (const float*)&v0;
        const float* p1 = (const float*)&v1;
#pragma unroll
        for (int j = 0; j < 4; ++j) o.s[j]     = f32_to_bf16(p0[j]);
#pragma unroll
        for (int j = 0; j < 4; ++j) o.s[4 + j] = f32_to_bf16(p1[j]);
        *(int4*)(xb + e0) = o.v;
    }
}

// ---------------------------------------------------------------------------
// GEMM: 256x256 tile, BK=32, 8 waves (2Mx4N), 16x16x32 MFMA, 3 LDS buffers.
// ONE barrier + ONE vmcnt per K-tile; reads+MFMA free-flow so waves skew
// within the tile and LDS service overlaps MFMA across waves.
// C[m][o] = sum_k A[m][k]*B[o][k] + bias[o]
// ---------------------------------------------------------------------------
__global__ __launch_bounds__(512, 2) void gemm_ff(
        const u16* __restrict__ A,    // M x K bf16
        const u16* __restrict__ Bm,   // N x K bf16 (B^T)
        const float* __restrict__ bias,
        float* __restrict__ C) {
    // 3 buffers x (A 16KB + B 16KB) = 96KB. [256 rows][32 cols] bf16 each.
    __shared__ __align__(16) u16 ldsA3[3][8192];
    __shared__ __align__(16) u16 ldsB3[3][8192];

    const int tid = threadIdx.x;
    const int bid = blockIdx.x;
    // bijective XCD swizzle (nwg = 1024, %8==0)
    const int swz = (bid & 7) * 128 + (bid >> 3);
    const int tm = swz >> 4;          // 64 M-tiles
    const int tn = swz & 15;          // 16 N-tiles
    const int mBase = tm * 256;
    const int nBase = tn * 256;

    const int lane = tid & 63;
    const int wave = tid >> 6;
    const int wr = wave >> 2;         // 0..1  (M half)
    const int wc = wave & 3;          // 0..3  (N quarter)

    // ---- staging (write side): linear LDS dest, inverse-swizzled source ----
    const int srow = tid >> 2;                        // 0..127
    const int slog = (tid & 3) ^ ((srow >> 1) & 3);   // logical 16B slot
    const u16* aS0 = A  + (size_t)(mBase + srow)       * K_DIM + slog * 8;
    const u16* aS1 = A  + (size_t)(mBase + srow + 128) * K_DIM + slog * 8;
    const u16* bS0 = Bm + (size_t)(nBase + srow)       * K_DIM + slog * 8;
    const u16* bS1 = Bm + (size_t)(nBase + srow + 128) * K_DIM + slog * 8;

    // 4 gloads per tile per thread: A lo/hi rows, B lo/hi rows
#define STAGE(buf, t) do { const size_t _k = (size_t)(t) * 32;          \
        gload16(aS0 + _k, &ldsA3[buf][tid * 8]);                        \
        gload16(aS1 + _k, &ldsA3[buf][4096 + tid * 8]);                 \
        gload16(bS0 + _k, &ldsB3[buf][tid * 8]);                        \
        gload16(bS1 + _k, &ldsB3[buf][4096 + tid * 8]); } while (0)

    // ---- fragment read bases (swizzled) — proven conflict-free pattern ----
    const int rl = lane & 15, cbk = lane >> 4;        // row-in-frag, k-group
    const int sslot = cbk ^ ((rl >> 1) & 3);
    const int aRd = (wr * 128 + rl) * 32 + sslot * 8;  // ushort offset
    const int bRd = (wc * 64  + rl) * 32 + sslot * 8;

    f32x4 acc[8][4] = {};
    bf16x8 af0, af1, af2, af3, af4, af5, af6, af7;
    bf16x8 bf0, bf1, bf2, bf3;

#define MM(m, n) acc[m][n] = __builtin_amdgcn_mfma_f32_16x16x32_bf16(af##m, bf##n, acc[m][n], 0, 0, 0)

    // ---- prologue: stage tiles 0,1 into bufs 0,1 ----
    STAGE(0, 0);
    STAGE(1, 1);

    int cur = 0, nx1 = 1, nx2 = 2;
    for (int t = 0; t < NT32; ++t) {
        // drain stage(t) (leave stage(t+1)'s 4 in flight), then certify
        // cross-wave: all waves' stage(t) landed AND all t-1 reads drained.
        asm volatile("s_waitcnt vmcnt(4)" ::: "memory");
        __builtin_amdgcn_s_barrier();

        // stage t+2 into the buffer whose last readers were tile t-1
        const int ts = (t + 2 < NT32) ? t + 2 : NT32 - 1;
        STAGE(nx2, ts);

        // free-flow: 12 ds_read_b128 + 32 MFMA, compiler-counted lgkmcnt
        const u16* pA = &ldsA3[cur][0];
        const u16* pB = &ldsB3[cur][0];
        bf0 = *(const bf16x8*)&pB[bRd];          bf1 = *(const bf16x8*)&pB[bRd + 512];
        bf2 = *(const bf16x8*)&pB[bRd + 1024];   bf3 = *(const bf16x8*)&pB[bRd + 1536];
        af0 = *(const bf16x8*)&pA[aRd];          af1 = *(const bf16x8*)&pA[aRd + 512];
        af2 = *(const bf16x8*)&pA[aRd + 1024];   af3 = *(const bf16x8*)&pA[aRd + 1536];
        af4 = *(const bf16x8*)&pA[aRd + 2048];   af5 = *(const bf16x8*)&pA[aRd + 2560];
        af6 = *(const bf16x8*)&pA[aRd + 3072];   af7 = *(const bf16x8*)&pA[aRd + 3584];

        __builtin_amdgcn_s_setprio(1);
        MM(0, 0); MM(0, 1); MM(0, 2); MM(0, 3);
        MM(1, 0); MM(1, 1); MM(1, 2); MM(1, 3);
        MM(2, 0); MM(2, 1); MM(2, 2); MM(2, 3);
        MM(3, 0); MM(3, 1); MM(3, 2); MM(3, 3);
        MM(4, 0); MM(4, 1); MM(4, 2); MM(4, 3);
        MM(5, 0); MM(5, 1); MM(5, 2); MM(5, 3);
        MM(6, 0); MM(6, 1); MM(6, 2); MM(6, 3);
        MM(7, 0); MM(7, 1); MM(7, 2); MM(7, 3);
        __builtin_amdgcn_s_setprio(0);
        __builtin_amdgcn_sched_barrier(0);

        const int tmp = cur; cur = nx1; nx1 = nx2; nx2 = tmp;
    }
    asm volatile("s_waitcnt vmcnt(0) lgkmcnt(0)" ::: "memory");

    // ---- epilogue: C/D layout col=lane&15, row=(lane>>4)*4+j ----
#pragma unroll
    for (int n = 0; n < 4; ++n) {
        const int col = nBase + wc * 64 + n * 16 + rl;
        const float bv = bias[col];
#pragma unroll
        for (int m = 0; m < 8; ++m) {
            const int row = mBase + wr * 128 + m * 16 + cbk * 4;
#pragma unroll
            for (int j = 0; j < 4; ++j)
                C[(size_t)(row + j) * N_DIM + col] = acc[m][n][j] + bv;
        }
    }
#undef STAGE
#undef MM
}

// ---------------------------------------------------------------------------
// Fallback (only if ws_size too small): correct but slow
// ---------------------------------------------------------------------------
__global__ void naive_fallback(const float* __restrict__ x,
                               const float* __restrict__ W0,
                               const float* __restrict__ b,
                               const float* __restrict__ w1,
                               const float* __restrict__ w2a,
                               const float* __restrict__ w2b,
                               float* __restrict__ out) {
    __shared__ float w2s[64 * 64];
    for (int t = threadIdx.x; t < 4096; t += blockDim.x) {
        int rr = t >> 6, cc = t & 63;
        float s = 0.f;
        for (int k = 0; k < 4; ++k) s += w2a[rr * 4 + k] * w2b[k * 64 + cc];
        w2s[t] = s * 0.25f;
    }
    __syncthreads();
    long idx = (long)blockIdx.x * blockDim.x + threadIdx.x;
    int m = (int)(idx >> 12);
    int o = (int)(idx & 4095);
    const float* xr = x + (long)m * K_DIM;
    const float* wrp = W0 + (long)o * K_DIM;
    int ob = (o >> 6) * 64, orr = (o & 63) * 64;
    float acc = 0.f;
    for (int i = 0; i < K_DIM; ++i) {
        float w = wrp[i] + w1[ob + (i >> 6)] * w2s[orr + (i & 63)];
        acc += xr[i] * w;
    }
    out[idx] = acc + b[o];
}

extern "C" void kernel_launch(void* const* d_in, const int* in_sizes, int n_in,
                              void* d_out, int out_size, void* d_ws, size_t ws_size,
                              hipStream_t stream) {
    const float* x   = (const float*)d_in[0];
    const float* W0  = (const float*)d_in[1];
    const float* b   = (const float*)d_in[2];
    const float* w1  = (const float*)d_in[3];
    const float* w2a = (const float*)d_in[4];
    const float* w2b = (const float*)d_in[5];
    float* out = (float*)d_out;

    const size_t xb_bytes = (size_t)M_DIM * K_DIM * 2;   // 128 MB
    const size_t wf_bytes = (size_t)N_DIM * K_DIM * 2;   // 32 MB

    if (ws_size >= xb_bytes + wf_bytes) {
        u16* xb = (u16*)d_ws;
        u16* wf = (u16*)((char*)d_ws + xb_bytes);
        prep<<<49152, 256, 0, stream>>>(W0, w1, w2a, w2b, x, wf, xb);
        gemm_ff<<<(M_DIM / 256) * (N_DIM / 256), 512, 0, stream>>>(xb, wf, b, out);
    } else {
        naive_fallback<<<((long)M_DIM * N_DIM) / 256, 256, 0, stream>>>(
            x, W0, b, w1, w2a, w2b, out);
    }
}